// Round 2
// 264.171 us; speedup vs baseline: 1.0125x; 1.0125x over previous
//
#include <hip/hip_runtime.h>
#include <cstdint>
#include <cstddef>

// GCN 2-layer:
//   h   = relu(Agg(x@W1) + b1);  out = Agg(h@W2) + b2
//   Agg(z)[i] = dinv[i] * ( dinv[i]*z[i] + sum_{e: col(e)=i} dinv[row(e)]*z[row(e)] )
//   dinv[i] = rsqrt(1 + indeg(i))
// Factorization: xws = dinv ⊙ (A@W) (scaled in GEMM epilogue, bf16);
//   Agg reduces to out[i] = dinv[i]*(xws[i] + Σ_{nbr r} xws[r]) + b.
//
// R2 (post cooperative-launch failure — hipLaunchCooperativeKernel is NOT
// graph-capture-safe in this harness; reverted to regular launches):
//  - setup: fused zero+Wt-transpose+zero-row kernel (7 -> 6 setup launches)
//  - aggregate: mask-free gather via zero row at index N (dummy edges read
//    exact 0.0f; numerics identical), bias/dinv loads hoisted ahead of loop

typedef unsigned int u32;
typedef unsigned short u16;
typedef __attribute__((ext_vector_type(8))) short short8;   // 8 bf16 (4 VGPRs)
typedef __attribute__((ext_vector_type(4))) float f32x4;    // MFMA acc

__device__ __forceinline__ float bf2f(u32 lo16) {
  union { u32 u; float f; } c; c.u = lo16 << 16; return c.f;
}
__device__ __forceinline__ u32 f2bf(float f) {  // round-to-nearest-even
  union { float f; u32 u; } c; c.f = f;
  return (c.u + 0x7fffu + ((c.u >> 16) & 1u)) >> 16;
}

// phase 0 fused: zero cnt[N]; W1,W2 [k][n] f32 -> Wt [n][k] bf16; zero row N.
__global__ __launch_bounds__(256) void zero_wt_kernel(
    const float* __restrict__ W1, const float* __restrict__ W2,
    u16* __restrict__ Wt1, u16* __restrict__ Wt2, u16* __restrict__ bufXW,
    int* __restrict__ cnt, int N) {
  int gt = blockIdx.x * 256 + threadIdx.x;
  if (gt < N) cnt[gt] = 0;
  if (gt < 32768) {
    const float* W = (gt < 16384) ? W1 : W2;
    u16* Wt = (gt < 16384) ? Wt1 : Wt2;
    int idx = gt & 16383;
    Wt[(idx & 127) * 128 + (idx >> 7)] = (u16)f2bf(W[idx]);
  }
  if (gt < 16) ((uint4*)(bufXW + (size_t)N * 128))[gt] = make_uint4(0, 0, 0, 0);
}

__global__ __launch_bounds__(256) void count_kernel(
    const int* __restrict__ cols, const int* __restrict__ rows,
    int* __restrict__ cnt, int E, int N) {
  int e = blockIdx.x * 256 + threadIdx.x;
  if (e >= E) return;
  int c = cols[e];
  int r = rows[e];
  if ((unsigned)c >= (unsigned)N || (unsigned)r >= (unsigned)N) return;
  atomicAdd(&cnt[c], 1);
}

// ---- exclusive scan of cnt[N] -> rowptr[N]; also emits dinv (fused)
__global__ __launch_bounds__(256) void scan1_kernel(
    const int* __restrict__ cnt, int* __restrict__ rowptr,
    int* __restrict__ bsum, float* __restrict__ dinv, int N) {
  __shared__ int sd[256];
  int t = threadIdx.x;
  int base = blockIdx.x * 1024 + t * 4;
  int c0 = (base + 0 < N) ? cnt[base + 0] : 0;
  int c1 = (base + 1 < N) ? cnt[base + 1] : 0;
  int c2 = (base + 2 < N) ? cnt[base + 2] : 0;
  int c3 = (base + 3 < N) ? cnt[base + 3] : 0;
  if (base + 0 < N) dinv[base + 0] = rsqrtf((float)c0 + 1.0f);
  if (base + 1 < N) dinv[base + 1] = rsqrtf((float)c1 + 1.0f);
  if (base + 2 < N) dinv[base + 2] = rsqrtf((float)c2 + 1.0f);
  if (base + 3 < N) dinv[base + 3] = rsqrtf((float)c3 + 1.0f);
  int s = c0 + c1 + c2 + c3;
  sd[t] = s;
  __syncthreads();
  for (int off = 1; off < 256; off <<= 1) {
    int v = (t >= off) ? sd[t - off] : 0;
    __syncthreads();
    sd[t] += v;
    __syncthreads();
  }
  int excl = sd[t] - s;
  if (base + 0 < N) rowptr[base + 0] = excl;
  if (base + 1 < N) rowptr[base + 1] = excl + c0;
  if (base + 2 < N) rowptr[base + 2] = excl + c0 + c1;
  if (base + 3 < N) rowptr[base + 3] = excl + c0 + c1 + c2;
  if (t == 255) bsum[blockIdx.x] = sd[255];
}

__global__ __launch_bounds__(128) void scan2_kernel(
    const int* __restrict__ bsum, int* __restrict__ bsum2,
    int* __restrict__ rowptr, int NB, int N) {
  __shared__ int sd[128];
  int t = threadIdx.x;
  int v = (t < NB) ? bsum[t] : 0;
  sd[t] = v;
  __syncthreads();
  for (int off = 1; off < 128; off <<= 1) {
    int u = (t >= off) ? sd[t - off] : 0;
    __syncthreads();
    sd[t] += u;
    __syncthreads();
  }
  bsum2[t] = sd[t] - v;
  if (t == NB - 1) rowptr[N] = sd[t];
}

__global__ __launch_bounds__(256) void scan3_kernel(
    int* __restrict__ rowptr, const int* __restrict__ bsum2, int N) {
  int t = threadIdx.x;
  int b = blockIdx.x;
  int base = b * 1024 + t * 4;
  int add = bsum2[b];
#pragma unroll
  for (int k = 0; k < 4; k++)
    if (base + k < N) rowptr[base + k] += add;
}

// cnt doubles as the cursor: atomicSub returns old count, pos = old-1 in [0,deg)
__global__ __launch_bounds__(256) void fill_kernel(
    const int* __restrict__ cols, const int* __restrict__ rows,
    const int* __restrict__ rowptr, int* __restrict__ cnt,
    int* __restrict__ adj, int E, int N) {
  int e = blockIdx.x * 256 + threadIdx.x;
  if (e >= E) return;
  int c = cols[e];
  int r = rows[e];
  if ((unsigned)c >= (unsigned)N || (unsigned)r >= (unsigned)N) return;
  int pos = atomicSub(&cnt[c], 1) - 1;
  if (pos >= 0) adj[rowptr[c] + pos] = r;
}

// ---------------------------------------------------------------------------
// C_bf16[M,128] = dinv[row] * (A[M,128] @ W[128,128]) via MFMA 16x16x32 bf16.
// Block = 256 thr (4 waves), tile 128 rows; wave w owns rows w*32..+31
// (2 m-tiles) x 128 cols (8 n-tiles). Wt staged once in LDS [n][k] pad 136.
// A fragments straight from global (each byte read once; no k-loop barrier).
// Epilogue: scaled bf16 tile round-trips through Ws (dead after k-loop) so
// global stores are coalesced uint4.
// Fragment layouts (m89/m118-verified):
//   A: lane holds A[m=lane&15][k=quad*8+j];  B: B[k=quad*8+j][n=lane&15]
//   C/D: col=lane&15, row=quad*4+reg
// ---------------------------------------------------------------------------
template <int A_BF16>
__global__ __launch_bounds__(256) void gemm_mfma_kernel(
    const void* __restrict__ Av, const u16* __restrict__ Wt,
    const float* __restrict__ dinv, u16* __restrict__ C, int M) {
  __shared__ u16 Ws[128][136];
  __shared__ float dv_s[128];
  const int tid = threadIdx.x;
  const int row0 = blockIdx.x * 128;

  {
    const uint4* src = (const uint4*)Wt;  // 2048 x 16B
#pragma unroll
    for (int i = 0; i < 8; i++) {
      int linear = tid + i * 256;
      int n = linear >> 4;
      int kq = linear & 15;
      *(uint4*)&Ws[n][kq * 8] = src[linear];
    }
  }
  if (tid < 128) {
    int gr = row0 + tid;
    dv_s[tid] = (gr < M) ? dinv[gr] : 0.f;
  }
  __syncthreads();

  const int wave = tid >> 6;
  const int lane = tid & 63;
  const int lm = lane & 15;
  const int quad = lane >> 4;
  const int m0 = wave * 32;

  f32x4 acc[2][8];
#pragma unroll
  for (int mt = 0; mt < 2; mt++)
#pragma unroll
    for (int nt = 0; nt < 8; nt++) acc[mt][nt] = (f32x4){0.f, 0.f, 0.f, 0.f};

#pragma unroll
  for (int k0 = 0; k0 < 128; k0 += 32) {
    short8 bfrag[8];
#pragma unroll
    for (int nt = 0; nt < 8; nt++)
      bfrag[nt] = *(const short8*)&Ws[nt * 16 + lm][k0 + quad * 8];

    short8 afrag[2];
#pragma unroll
    for (int mt = 0; mt < 2; mt++) {
      int gr = row0 + m0 + mt * 16 + lm;
      short8 f = (short8){0, 0, 0, 0, 0, 0, 0, 0};
      if (gr < M) {
        if (A_BF16) {
          f = *(const short8*)((const u16*)Av + (size_t)gr * 128 + k0 + quad * 8);
        } else {
          const float* Af = (const float*)Av + (size_t)gr * 128 + k0 + quad * 8;
          float4 v0 = *(const float4*)Af;
          float4 v1 = *(const float4*)(Af + 4);
          f[0] = (short)f2bf(v0.x); f[1] = (short)f2bf(v0.y);
          f[2] = (short)f2bf(v0.z); f[3] = (short)f2bf(v0.w);
          f[4] = (short)f2bf(v1.x); f[5] = (short)f2bf(v1.y);
          f[6] = (short)f2bf(v1.z); f[7] = (short)f2bf(v1.w);
        }
      }
      afrag[mt] = f;
    }

#pragma unroll
    for (int mt = 0; mt < 2; mt++)
#pragma unroll
      for (int nt = 0; nt < 8; nt++)
        acc[mt][nt] = __builtin_amdgcn_mfma_f32_16x16x32_bf16(
            afrag[mt], bfrag[nt], acc[mt][nt], 0, 0, 0);
  }

  // epilogue: scale by dinv[row], pack bf16 into Ws (dead), store coalesced
  __syncthreads();  // all waves done reading Ws
#pragma unroll
  for (int mt = 0; mt < 2; mt++) {
    int rbase = m0 + mt * 16 + quad * 4;
#pragma unroll
    for (int r = 0; r < 4; r++) {
      int lrow = rbase + r;
      float dv = dv_s[lrow];
#pragma unroll
      for (int nt = 0; nt < 8; nt++)
        Ws[lrow][nt * 16 + lm] = (u16)f2bf(acc[mt][nt][r] * dv);
    }
  }
  __syncthreads();
#pragma unroll
  for (int i = 0; i < 8; i++) {
    int linear = tid + i * 256;  // 0..2047
    int row = linear >> 4;
    int c8 = linear & 15;        // 8-col chunk
    int grow = row0 + row;
    if (grow < M)
      *(uint4*)(C + (size_t)grow * 128 + c8 * 8) = *(const uint4*)&Ws[row][c8 * 8];
  }
}

// ---------------------------------------------------------------------------
// Quarter-wave (16 lanes) per node; lane owns cols 8l..8l+7 (uint4 = 8 bf16).
// 4 independent node chains per wave + unroll-8 -> 32 outstanding 16B gathers.
// Mask-free: dummy edges (jj >= end) gather the zeroed row at index N.
// ---------------------------------------------------------------------------
template <int RELU, int OUT_BF16>
__global__ __launch_bounds__(256) void aggregate_kernel(
    const uint4* __restrict__ xws, const int* __restrict__ rowptr,
    const int* __restrict__ adj, const float* __restrict__ dinv,
    const float* __restrict__ bias, void* __restrict__ out, int N) {
  int node = blockIdx.x * 16 + (threadIdx.x >> 4);
  if (node >= N) return;
  int lane = threadIdx.x & 15;

  int beg = rowptr[node];
  int end = rowptr[node + 1];
  float di = dinv[node];
  float4 b0 = ((const float4*)bias)[lane * 2];
  float4 b1 = ((const float4*)bias)[lane * 2 + 1];

  float a[8];
  {
    uint4 sv = xws[(size_t)node * 16 + lane];
    a[0] = bf2f(sv.x & 0xffff); a[1] = bf2f(sv.x >> 16);
    a[2] = bf2f(sv.y & 0xffff); a[3] = bf2f(sv.y >> 16);
    a[4] = bf2f(sv.z & 0xffff); a[5] = bf2f(sv.z >> 16);
    a[6] = bf2f(sv.w & 0xffff); a[7] = bf2f(sv.w >> 16);
  }

  for (int j = beg; j < end; j += 8) {
    int sidx[8];
#pragma unroll
    for (int k = 0; k < 8; k++) {
      int jj = j + k;
      sidx[k] = (jj < end) ? adj[jj] : N;  // N = zero row (exact 0.0 adds)
    }
    uint4 v[8];
#pragma unroll
    for (int k = 0; k < 8; k++) v[k] = xws[(size_t)sidx[k] * 16 + lane];
#pragma unroll
    for (int k = 0; k < 8; k++) {
      a[0] += bf2f(v[k].x & 0xffff); a[1] += bf2f(v[k].x >> 16);
      a[2] += bf2f(v[k].y & 0xffff); a[3] += bf2f(v[k].y >> 16);
      a[4] += bf2f(v[k].z & 0xffff); a[5] += bf2f(v[k].z >> 16);
      a[6] += bf2f(v[k].w & 0xffff); a[7] += bf2f(v[k].w >> 16);
    }
  }

  float o[8];
  o[0] = fmaf(di, a[0], b0.x); o[1] = fmaf(di, a[1], b0.y);
  o[2] = fmaf(di, a[2], b0.z); o[3] = fmaf(di, a[3], b0.w);
  o[4] = fmaf(di, a[4], b1.x); o[5] = fmaf(di, a[5], b1.y);
  o[6] = fmaf(di, a[6], b1.z); o[7] = fmaf(di, a[7], b1.w);
  if (RELU) {
#pragma unroll
    for (int k = 0; k < 8; k++) o[k] = fmaxf(o[k], 0.f);
  }
  if (OUT_BF16) {
    uint4 p;
    p.x = f2bf(o[0]) | (f2bf(o[1]) << 16);
    p.y = f2bf(o[2]) | (f2bf(o[3]) << 16);
    p.z = f2bf(o[4]) | (f2bf(o[5]) << 16);
    p.w = f2bf(o[6]) | (f2bf(o[7]) << 16);
    ((uint4*)out)[(size_t)node * 16 + lane] = p;
  } else {
    float4* op = (float4*)out + (size_t)node * 32 + lane * 2;
    op[0] = make_float4(o[0], o[1], o[2], o[3]);
    op[1] = make_float4(o[4], o[5], o[6], o[7]);
  }
}

extern "C" void kernel_launch(void* const* d_in, const int* in_sizes, int n_in,
                              void* d_out, int out_size, void* d_ws, size_t ws_size,
                              hipStream_t stream) {
  const float* x  = (const float*)d_in[0];
  const int*   ei = (const int*)d_in[1];
  const float* W1 = (const float*)d_in[2];
  const float* b1 = (const float*)d_in[3];
  const float* W2 = (const float*)d_in[4];
  const float* b2 = (const float*)d_in[5];
  float* out = (float*)d_out;

  const int F = 128;
  const int N = in_sizes[0] / F;
  const int E = in_sizes[1] / 2;
  const int* rows = ei;       // edge_index[0] = source
  const int* cols = ei + E;   // edge_index[1] = destination

  // workspace layout (~52.5 MB); Wt first for 16B alignment of uint4 loads
  u16*   Wt1    = (u16*)d_ws;                          // 128*128 bf16 (W1^T)
  u16*   Wt2    = Wt1 + 128 * 128;                     // 128*128 bf16 (W2^T)
  u16*   bufXW  = Wt2 + 128 * 128;                     // (N+1)*128 bf16 (xws + zero row)
  u16*   bufH   = bufXW + (size_t)(N + 1) * F;         // (N+1)*128 bf16 (h)
  float* dinv   = (float*)(bufH + (size_t)(N + 1) * F);// N f32
  int*   cnt    = (int*)(dinv + N);                    // N i32 (count, then cursor)
  int*   rowptr = cnt + N;                             // N+1 i32
  int*   adj    = rowptr + (N + 1);                    // E i32
  int*   bsum   = adj + E;                             // 128 i32
  int*   bsum2  = bsum + 128;                          // 128 i32

  const int NB = (N + 1023) / 1024;
  int eblocks = (E + 255) / 256;
  int nblocks = (N + 255) / 256;

  // build exact CSR + dinv; transpose/convert weights; zero row N
  zero_wt_kernel<<<nblocks, 256, 0, stream>>>(W1, W2, Wt1, Wt2, bufXW, cnt, N);
  count_kernel<<<eblocks, 256, 0, stream>>>(cols, rows, cnt, E, N);
  scan1_kernel<<<NB, 256, 0, stream>>>(cnt, rowptr, bsum, dinv, N);
  scan2_kernel<<<1, 128, 0, stream>>>(bsum, bsum2, rowptr, NB, N);
  scan3_kernel<<<NB, 256, 0, stream>>>(rowptr, bsum2, N);
  fill_kernel<<<eblocks, 256, 0, stream>>>(cols, rows, rowptr, cnt, adj, E, N);

  int gblocks = (N + 127) / 128;
  int ablocks = (N + 15) / 16;
  // layer 1: xws1 = dinv ⊙ (x@W1) (bf16) ; h = relu(dinv⊙Σ + b1) -> bufH (bf16)
  gemm_mfma_kernel<0><<<gblocks, 256, 0, stream>>>(x, Wt1, dinv, bufXW, N);
  aggregate_kernel<1, 1><<<ablocks, 256, 0, stream>>>(
      (const uint4*)bufXW, rowptr, adj, dinv, b1, bufH, N);
  // layer 2: xws2 = dinv ⊙ (h@W2) (bf16) ; out = dinv⊙Σ + b2 -> d_out (fp32)
  gemm_mfma_kernel<1><<<gblocks, 256, 0, stream>>>(bufH, Wt2, dinv, bufXW, N);
  aggregate_kernel<0, 0><<<ablocks, 256, 0, stream>>>(
      (const uint4*)bufXW, rowptr, adj, dinv, b2, out, N);
}

// Round 5
// 260.219 us; speedup vs baseline: 1.0279x; 1.0152x over previous
//
#include <hip/hip_runtime.h>
#include <cstdint>
#include <cstddef>

// GCN 2-layer, commuted form:  Agg(z) @ W == Agg(z @ W)  (Agg mixes rows, W mixes cols)
//   s1 = bf16(dinv ⊙ x)
//   h' = dinv ⊙ relu( [dinv ⊙ (s1_i + Σ_nbr s1_r)] @ W1 + b1 )   (bf16, pre-scaled for L2)
//   out =               [dinv ⊙ (h'_i + Σ_nbr h'_r)] @ W2 + b2    (fp32)
// Each layer = ONE fused kernel: gather 64 node-rows -> LDS (bf16, dinv-scaled),
// barrier, MFMA vs W (LDS), epilogue (bias/relu/dinv) -> coalesced store.
//
// R5: R3/R4's failures were a COMPILE error (__builtin_nontemporal_store
// rejects HIP_vector_type float4). Fixed: store via native ext_vector f32x4.
// Design unchanged from R4: 64-node tile, 52.5 KiB LDS, 3 blocks/CU.

typedef unsigned int u32;
typedef unsigned short u16;
typedef __attribute__((ext_vector_type(8))) short short8;   // 8 bf16 (4 VGPRs)
typedef __attribute__((ext_vector_type(4))) float f32x4;    // MFMA acc / native vec

__device__ __forceinline__ float bf2f(u32 lo16) {
  union { u32 u; float f; } c; c.u = lo16 << 16; return c.f;
}
__device__ __forceinline__ u32 f2bf(float f) {  // round-to-nearest-even
  union { float f; u32 u; } c; c.f = f;
  return (c.u + 0x7fffu + ((c.u >> 16) & 1u)) >> 16;
}

// zero cnt; W1,W2 [k][n] f32 -> Wt [n][k] bf16; zero row N of s1 and hp.
__global__ __launch_bounds__(256) void zero_wt_kernel(
    const float* __restrict__ W1, const float* __restrict__ W2,
    u16* __restrict__ Wt1, u16* __restrict__ Wt2,
    u16* __restrict__ s1, u16* __restrict__ hp,
    int* __restrict__ cnt, int N) {
  int gt = blockIdx.x * 256 + threadIdx.x;
  if (gt < N) cnt[gt] = 0;
  if (gt < 32768) {
    const float* W = (gt < 16384) ? W1 : W2;
    u16* Wt = (gt < 16384) ? Wt1 : Wt2;
    int idx = gt & 16383;
    Wt[(idx & 127) * 128 + (idx >> 7)] = (u16)f2bf(W[idx]);
  }
  if (gt < 16) {
    ((uint4*)(s1 + (size_t)N * 128))[gt] = make_uint4(0, 0, 0, 0);
    ((uint4*)(hp + (size_t)N * 128))[gt] = make_uint4(0, 0, 0, 0);
  }
}

__global__ __launch_bounds__(256) void count_kernel(
    const int* __restrict__ cols, const int* __restrict__ rows,
    int* __restrict__ cnt, int E, int N) {
  int e = blockIdx.x * 256 + threadIdx.x;
  if (e >= E) return;
  int c = cols[e];
  int r = rows[e];
  if ((unsigned)c >= (unsigned)N || (unsigned)r >= (unsigned)N) return;
  atomicAdd(&cnt[c], 1);
}

// exclusive scan of cnt[N] -> rowptr[N] (chunk-local); emits dinv (fused)
__global__ __launch_bounds__(256) void scan1_kernel(
    const int* __restrict__ cnt, int* __restrict__ rowptr,
    int* __restrict__ bsum, float* __restrict__ dinv, int N) {
  __shared__ int sd[256];
  int t = threadIdx.x;
  int base = blockIdx.x * 1024 + t * 4;
  int c0 = (base + 0 < N) ? cnt[base + 0] : 0;
  int c1 = (base + 1 < N) ? cnt[base + 1] : 0;
  int c2 = (base + 2 < N) ? cnt[base + 2] : 0;
  int c3 = (base + 3 < N) ? cnt[base + 3] : 0;
  if (base + 0 < N) dinv[base + 0] = rsqrtf((float)c0 + 1.0f);
  if (base + 1 < N) dinv[base + 1] = rsqrtf((float)c1 + 1.0f);
  if (base + 2 < N) dinv[base + 2] = rsqrtf((float)c2 + 1.0f);
  if (base + 3 < N) dinv[base + 3] = rsqrtf((float)c3 + 1.0f);
  int s = c0 + c1 + c2 + c3;
  sd[t] = s;
  __syncthreads();
  for (int off = 1; off < 256; off <<= 1) {
    int v = (t >= off) ? sd[t - off] : 0;
    __syncthreads();
    sd[t] += v;
    __syncthreads();
  }
  int excl = sd[t] - s;
  if (base + 0 < N) rowptr[base + 0] = excl;
  if (base + 1 < N) rowptr[base + 1] = excl + c0;
  if (base + 2 < N) rowptr[base + 2] = excl + c0 + c1;
  if (base + 3 < N) rowptr[base + 3] = excl + c0 + c1 + c2;
  if (t == 255) bsum[blockIdx.x] = sd[255];
}

__global__ __launch_bounds__(128) void scan2_kernel(
    const int* __restrict__ bsum, int* __restrict__ bsum2,
    int* __restrict__ rowptr, int NB, int N) {
  __shared__ int sd[128];
  int t = threadIdx.x;
  int v = (t < NB) ? bsum[t] : 0;
  sd[t] = v;
  __syncthreads();
  for (int off = 1; off < 128; off <<= 1) {
    int u = (t >= off) ? sd[t - off] : 0;
    __syncthreads();
    sd[t] += u;
    __syncthreads();
  }
  bsum2[t] = sd[t] - v;
  if (t == NB - 1) rowptr[N] = sd[t];
}

// rowptr += chunk offset (scan3)  AND  s1 = bf16(dinv ⊙ x)  (fused)
__global__ __launch_bounds__(256) void finalize_kernel(
    const float* __restrict__ x, const float* __restrict__ dinv,
    int* __restrict__ rowptr, const int* __restrict__ bsum2,
    u16* __restrict__ s1, int N, int NB) {
  int b = blockIdx.x, t = threadIdx.x;
  if (b < NB) {
    int base = b * 1024 + t * 4;
    int add = bsum2[b];
#pragma unroll
    for (int k = 0; k < 4; k++)
      if (base + k < N) rowptr[base + k] += add;
  }
  int total = N * 16;  // 16B chunks per node row
  for (int idx = b * 256 + t; idx < total; idx += gridDim.x * 256) {
    int node = idx >> 4, l = idx & 15;
    float di = dinv[node];
    const float* xp = x + (size_t)node * 128 + l * 8;
    float4 v0 = *(const float4*)xp;
    float4 v1 = *(const float4*)(xp + 4);
    uint4 p;
    p.x = f2bf(di * v0.x) | (f2bf(di * v0.y) << 16);
    p.y = f2bf(di * v0.z) | (f2bf(di * v0.w) << 16);
    p.z = f2bf(di * v1.x) | (f2bf(di * v1.y) << 16);
    p.w = f2bf(di * v1.z) | (f2bf(di * v1.w) << 16);
    ((uint4*)s1)[idx] = p;
  }
}

// cnt doubles as the cursor: atomicSub returns old count, pos = old-1 in [0,deg)
__global__ __launch_bounds__(256) void fill_kernel(
    const int* __restrict__ cols, const int* __restrict__ rows,
    const int* __restrict__ rowptr, int* __restrict__ cnt,
    int* __restrict__ adj, int E, int N) {
  int e = blockIdx.x * 256 + threadIdx.x;
  if (e >= E) return;
  int c = cols[e];
  int r = rows[e];
  if ((unsigned)c >= (unsigned)N || (unsigned)r >= (unsigned)N) return;
  int pos = atomicSub(&cnt[c], 1) - 1;
  if (pos >= 0) adj[rowptr[c] + pos] = r;
}

// ---------------------------------------------------------------------------
// Fused aggregate + GEMM. Block = 256 thr, 64 nodes. LDS 52.5 KiB -> 3/CU.
// Phase 1 (gather): quarter-wave per node, 4 passes; fp32 accumulate of
//   src[self] + Σ src[nbr] (zero-row N pads dummies); write dinv*g to
//   Gs (bf16, LDS). Mask-free. W tile (128x128) staged to Ws concurrently.
// Phase 2 (MFMA): 4 waves; wave owns 16 rows (1 m-tile) x 8 nt x 4 k-steps
//   of 16x16x32 bf16, A from Gs, B from Ws. Layouts (m89/m118-verified):
//   A: lane holds A[m=lane&15][k=quad*8+j];  B: B[k=quad*8+j][n=lane&15]
//   C/D: col=lane&15, row=quad*4+reg
// Epilogue L1: hp = bf16(dinv*relu(acc+b1)) via Gs reuse, coalesced uint4.
// Epilogue L2: out = fp32(acc+b2) via fp32 overlay of Ws, nontemporal f32x4.
// ---------------------------------------------------------------------------
template <int LAYER>
__global__ __launch_bounds__(256) void fused_ag_kernel(
    const uint4* __restrict__ src, const int* __restrict__ rowptr,
    const int* __restrict__ adj, const float* __restrict__ dinv,
    const float* __restrict__ bias, const uint4* __restrict__ Wt,
    void* __restrict__ out, int N) {
  __shared__ __align__(16) u16 smem[128 * 136 + 64 * 136];  // Ws | Gs
  __shared__ float dv_s[64];
  u16 (*Ws)[136] = (u16(*)[136])smem;                 // 34816 B (W, [n][k])
  u16 (*Gs)[136] = (u16(*)[136])(smem + 128 * 136);   // 17408 B (gathered rows)
  const int tid = threadIdx.x;
  const int row0 = blockIdx.x * 64;

  // stage W tile (2048 x 16B)
#pragma unroll
  for (int i = 0; i < 8; i++) {
    int linear = tid + i * 256;
    int n = linear >> 4, kq = linear & 15;
    *(uint4*)&Ws[n][kq * 8] = Wt[linear];
  }

  // ---- gather phase: 4 passes x 16 nodes (quarter-wave per node)
  const int qw = tid >> 4;
  const int l = tid & 15;
#pragma unroll
  for (int pass = 0; pass < 4; ++pass) {
    int lrow = pass * 16 + qw;
    int node = row0 + lrow;
    float a[8] = {0.f, 0.f, 0.f, 0.f, 0.f, 0.f, 0.f, 0.f};
    float di = 0.f;
    if (node < N) {
      di = dinv[node];
      uint4 sv = src[(size_t)node * 16 + l];
      a[0] = bf2f(sv.x & 0xffff); a[1] = bf2f(sv.x >> 16);
      a[2] = bf2f(sv.y & 0xffff); a[3] = bf2f(sv.y >> 16);
      a[4] = bf2f(sv.z & 0xffff); a[5] = bf2f(sv.z >> 16);
      a[6] = bf2f(sv.w & 0xffff); a[7] = bf2f(sv.w >> 16);
      int beg = rowptr[node], end = rowptr[node + 1];
      for (int j = beg; j < end; j += 8) {
        int sidx[8];
#pragma unroll
        for (int k = 0; k < 8; k++) {
          int jj = j + k;
          sidx[k] = (jj < end) ? adj[jj] : N;  // N = zero row
        }
        uint4 v[8];
#pragma unroll
        for (int k = 0; k < 8; k++) v[k] = src[(size_t)sidx[k] * 16 + l];
#pragma unroll
        for (int k = 0; k < 8; k++) {
          a[0] += bf2f(v[k].x & 0xffff); a[1] += bf2f(v[k].x >> 16);
          a[2] += bf2f(v[k].y & 0xffff); a[3] += bf2f(v[k].y >> 16);
          a[4] += bf2f(v[k].z & 0xffff); a[5] += bf2f(v[k].z >> 16);
          a[6] += bf2f(v[k].w & 0xffff); a[7] += bf2f(v[k].w >> 16);
        }
      }
    }
    uint4 p;
    p.x = f2bf(di * a[0]) | (f2bf(di * a[1]) << 16);
    p.y = f2bf(di * a[2]) | (f2bf(di * a[3]) << 16);
    p.z = f2bf(di * a[4]) | (f2bf(di * a[5]) << 16);
    p.w = f2bf(di * a[6]) | (f2bf(di * a[7]) << 16);
    *(uint4*)&Gs[lrow][l * 8] = p;
    if (l == 0) dv_s[lrow] = di;
  }
  __syncthreads();

  // ---- MFMA phase: wave owns rows m0..m0+15
  const int wave = tid >> 6, lane = tid & 63;
  const int lm = lane & 15, quad = lane >> 4;
  const int m0 = wave * 16;
  f32x4 acc[8];
#pragma unroll
  for (int nt = 0; nt < 8; nt++) acc[nt] = (f32x4){0.f, 0.f, 0.f, 0.f};
#pragma unroll
  for (int k0 = 0; k0 < 128; k0 += 32) {
    short8 afrag = *(const short8*)&Gs[m0 + lm][k0 + quad * 8];
#pragma unroll
    for (int nt = 0; nt < 8; nt++) {
      short8 bfrag = *(const short8*)&Ws[nt * 16 + lm][k0 + quad * 8];
      acc[nt] = __builtin_amdgcn_mfma_f32_16x16x32_bf16(afrag, bfrag, acc[nt], 0, 0, 0);
    }
  }

  float bv[8];
#pragma unroll
  for (int nt = 0; nt < 8; nt++) bv[nt] = bias[nt * 16 + lm];

  __syncthreads();  // Ws/Gs dead; reuse as epilogue staging
  if (LAYER == 1) {
    int rbase = m0 + quad * 4;
#pragma unroll
    for (int r = 0; r < 4; r++) {
      int lrow = rbase + r;
      float dv = dv_s[lrow];
#pragma unroll
      for (int nt = 0; nt < 8; nt++) {
        float v = fmaxf(acc[nt][r] + bv[nt], 0.f);
        Gs[lrow][nt * 16 + lm] = (u16)f2bf(v * dv);
      }
    }
    __syncthreads();
    u16* C = (u16*)out;
#pragma unroll
    for (int i = 0; i < 4; i++) {
      int linear = tid + i * 256;  // 0..1023
      int row = linear >> 4, c8 = linear & 15;
      int grow = row0 + row;
      if (grow < N)
        *(uint4*)(C + (size_t)grow * 128 + c8 * 8) = *(const uint4*)&Gs[row][c8 * 8];
    }
  } else {
    float (*Fs)[132] = (float(*)[132])smem;  // 64*132*4 = 33792 B (in Ws region)
    int rbase = m0 + quad * 4;
#pragma unroll
    for (int r = 0; r < 4; r++) {
      int lrow = rbase + r;
#pragma unroll
      for (int nt = 0; nt < 8; nt++)
        Fs[lrow][nt * 16 + lm] = acc[nt][r] + bv[nt];
    }
    __syncthreads();
    float* C = (float*)out;
#pragma unroll
    for (int i = 0; i < 8; i++) {
      int linear = tid + i * 256;  // 0..2047
      int row = linear >> 5, c4 = linear & 31;
      int grow = row0 + row;
      if (grow < N) {
        f32x4 v = *(const f32x4*)&Fs[row][c4 * 4];
        __builtin_nontemporal_store(v, (f32x4*)(C + (size_t)grow * 128 + c4 * 4));
      }
    }
  }
}

extern "C" void kernel_launch(void* const* d_in, const int* in_sizes, int n_in,
                              void* d_out, int out_size, void* d_ws, size_t ws_size,
                              hipStream_t stream) {
  const float* x  = (const float*)d_in[0];
  const int*   ei = (const int*)d_in[1];
  const float* W1 = (const float*)d_in[2];
  const float* b1 = (const float*)d_in[3];
  const float* W2 = (const float*)d_in[4];
  const float* b2 = (const float*)d_in[5];
  float* out = (float*)d_out;

  const int F = 128;
  const int N = in_sizes[0] / F;
  const int E = in_sizes[1] / 2;
  const int* rows = ei;       // edge_index[0] = source
  const int* cols = ei + E;   // edge_index[1] = destination

  // workspace layout (~55 MB)
  u16*   Wt1    = (u16*)d_ws;                          // 128*128 bf16 (W1^T)
  u16*   Wt2    = Wt1 + 128 * 128;                     // 128*128 bf16 (W2^T)
  u16*   s1     = Wt2 + 128 * 128;                     // (N+1)*128 bf16 (dinv⊙x + zero row)
  u16*   hp     = s1 + (size_t)(N + 1) * F;            // (N+1)*128 bf16 (dinv⊙h + zero row)
  float* dinv   = (float*)(hp + (size_t)(N + 1) * F);  // N f32
  int*   cnt    = (int*)(dinv + N);                    // N i32 (count, then cursor)
  int*   rowptr = cnt + N;                             // N+1 i32
  int*   adj    = rowptr + (N + 1);                    // E i32
  int*   bsum   = adj + E;                             // 128 i32
  int*   bsum2  = bsum + 128;                          // 128 i32

  const int NB = (N + 1023) / 1024;
  int eblocks = (E + 255) / 256;
  int nblocks = (N + 255) / 256;
  int fblocks = (NB > 784) ? NB : 784;

  zero_wt_kernel<<<nblocks, 256, 0, stream>>>(W1, W2, Wt1, Wt2, s1, hp, cnt, N);
  count_kernel<<<eblocks, 256, 0, stream>>>(cols, rows, cnt, E, N);
  scan1_kernel<<<NB, 256, 0, stream>>>(cnt, rowptr, bsum, dinv, N);
  scan2_kernel<<<1, 128, 0, stream>>>(bsum, bsum2, rowptr, NB, N);
  finalize_kernel<<<fblocks, 256, 0, stream>>>(x, dinv, rowptr, bsum2, s1, N, NB);
  fill_kernel<<<eblocks, 256, 0, stream>>>(cols, rows, rowptr, cnt, adj, E, N);

  int gblocks = (N + 63) / 64;
  // layer 1: hp = dinv ⊙ relu([dinv ⊙ Agg-sum(s1)] @ W1 + b1)  (bf16)
  fused_ag_kernel<1><<<gblocks, 256, 0, stream>>>(
      (const uint4*)s1, rowptr, adj, dinv, b1, (const uint4*)Wt1, hp, N);
  // layer 2: out = [dinv ⊙ Agg-sum(hp)] @ W2 + b2  (fp32)
  fused_ag_kernel<2><<<gblocks, 256, 0, stream>>>(
      (const uint4*)hp, rowptr, adj, dinv, b2, (const uint4*)Wt2, out, N);
}